// Round 10
// baseline (114.464 us; speedup 1.0000x reference)
//
#include <hip/hip_runtime.h>

#define CUT0 20000
#define CUT1 60000
#define D    1024
#define D1   256
#define D2   64
#define NTOK 32768

typedef __bf16  bf16x4 __attribute__((ext_vector_type(4)));
typedef __bf16  bf16x8 __attribute__((ext_vector_type(8)));
typedef float   f32x4  __attribute__((ext_vector_type(4)));

// ws layout: __bf16 w1b[D*D1], w2b[D*D2]  ([d][k] layout, MFMA A-operand rows)

__global__ __launch_bounds__(512) void k_cast(
        const float* __restrict__ w1, const float* __restrict__ w2,
        __bf16* __restrict__ w1b, __bf16* __restrict__ w2b) {
    int i = blockIdx.x * 512 + threadIdx.x;
    if (i < D * D1) w1b[i] = (__bf16)w1[i];
    else            w2b[i - D * D1] = (__bf16)w2[i - D * D1];
}

// Single fused kernel, 512-thr blocks.
// bid < 256: copy role (128 consecutive tokens each; c0 rows -> direct 4KB copy).
// bid >= 256: gemm role. gbid = bid-256 in [0,2048):
//   x = gbid&7 (XCD), h = (gbid>>3)&1 (d-half), y = gbid>>4; group = x*128+y.
//   Block = 32 consecutive tokens x 512 d. Per-wave tile 32tok x 64d, acc[4][2].
//   B1[32][256] = zero-masked bf16 emb1 rows; B2[32][64] = zero-masked emb2 rows.
//   Both passes accumulate into acc (out-of-cluster cols are exactly zero).
// Fragments (verified rounds 4-9):
//   A: lane holds w d-row wdb+t*16+(lane&15), k=(lane>>4)*8+j (+32/ks)
//   B: lane holds token col c*16+(lane&15), same k slots (LDS, chunk-XOR swz)
//   C/D: col=lane&15 (token), row=(lane>>4)*4+r (d) -> float4 store/lane
__global__ __launch_bounds__(512, 4) void k_mega(
        const int* __restrict__ ids,
        const float* __restrict__ emb0,
        const float* __restrict__ emb1,
        const float* __restrict__ emb2,
        const float* __restrict__ b1,
        const float* __restrict__ b2,
        const __bf16* __restrict__ w1b,
        const __bf16* __restrict__ w2b,
        float* __restrict__ out) {
    __shared__ __bf16 B1[32 * D1];   // 16 KB
    __shared__ __bf16 B2[32 * D2];   // 4 KB

    int bid = blockIdx.x, tid = threadIdx.x;

    if (bid < 256) {
        // ---- copy role: tokens [bid*128, bid*128+128) ----
        int cb = bid * 128;
        int sub = tid >> 8, f = tid & 255;
        for (int i = 0; i < 128; i += 2) {
            int tok = cb + i + sub;
            int id = ids[tok];
            if (id < CUT0) {
                const float4* src = (const float4*)(emb0 + (size_t)id * D);
                float4* dst = (float4*)(out + (size_t)tok * D);
                dst[f] = src[f];
            }
        }
        return;
    }

    int gbid = bid - 256;
    int x = gbid & 7, h = (gbid >> 3) & 1, y = gbid >> 4;
    int group = x * 128 + y;          // [0,1024)
    int gb = group * 32;              // token base

    // ---- gather phase: 32 rows, 16 threads/row ----
    {
        int r = tid >> 4, q = tid & 15;
        int id = ids[gb + r];
        bool is1 = (id >= CUT0) && (id < CUT1);
        bool is2 = (id >= CUT1);
        int l1 = is1 ? id - CUT0 : 0;
        int l2 = is2 ? id - CUT1 : 0;
        const float* s1 = emb1 + (size_t)l1 * D1 + q * 16;
#pragma unroll
        for (int f = 0; f < 4; f++) {
            float4 v = *(const float4*)(s1 + f * 4);
            if (!is1) { v.x = 0.f; v.y = 0.f; v.z = 0.f; v.w = 0.f; }
            bf16x4 w = { (__bf16)v.x, (__bf16)v.y, (__bf16)v.z, (__bf16)v.w };
            int k = q * 16 + f * 4;
            int chunk = (k >> 3) ^ (r & 15);
            *(bf16x4*)(B1 + r * D1 + chunk * 8 + (k & 7)) = w;
        }
        {
            float4 v = *(const float4*)(emb2 + (size_t)l2 * D2 + q * 4);
            if (!is2) { v.x = 0.f; v.y = 0.f; v.z = 0.f; v.w = 0.f; }
            bf16x4 w = { (__bf16)v.x, (__bf16)v.y, (__bf16)v.z, (__bf16)v.w };
            int k = q * 4;
            int chunk = (k >> 3) ^ (r & 7);
            *(bf16x4*)(B2 + r * D2 + chunk * 8 + (k & 7)) = w;
        }
    }
    __syncthreads();

    // ---- MFMA ----
    int lane = tid & 63, wv = tid >> 6;       // wv 0..7
    int row16 = lane & 15, kg = lane >> 4;
    int wdb = h * 512 + wv * 64;

    f32x4 acc[4][2];
#pragma unroll
    for (int t = 0; t < 4; t++)
#pragma unroll
        for (int c = 0; c < 2; c++) acc[t][c] = (f32x4){0.f, 0.f, 0.f, 0.f};

    // pass 1: w1 (K=256) over c1-masked B1
#pragma unroll
    for (int ks = 0; ks < 8; ks++) {
        bf16x8 b[2];
#pragma unroll
        for (int c = 0; c < 2; c++) {
            int rr = c * 16 + row16;
            int chunk = (kg + ks * 4) ^ (rr & 15);
            b[c] = *(const bf16x8*)(B1 + rr * D1 + chunk * 8);
        }
#pragma unroll
        for (int t = 0; t < 4; t++) {
            bf16x8 a = *(const bf16x8*)(w1b + (size_t)(wdb + t * 16 + row16) * D1 + kg * 8 + ks * 32);
#pragma unroll
            for (int c = 0; c < 2; c++)
                acc[t][c] = __builtin_amdgcn_mfma_f32_16x16x32_bf16(a, b[c], acc[t][c], 0, 0, 0);
        }
    }
    // pass 2: w2 (K=64) over c2-masked B2
#pragma unroll
    for (int ks = 0; ks < 2; ks++) {
        bf16x8 b[2];
#pragma unroll
        for (int c = 0; c < 2; c++) {
            int rr = c * 16 + row16;
            int chunk = (kg + ks * 4) ^ (rr & 7);
            b[c] = *(const bf16x8*)(B2 + rr * D2 + chunk * 8);
        }
#pragma unroll
        for (int t = 0; t < 4; t++) {
            bf16x8 a = *(const bf16x8*)(w2b + (size_t)(wdb + t * 16 + row16) * D2 + kg * 8 + ks * 32);
#pragma unroll
            for (int c = 0; c < 2; c++)
                acc[t][c] = __builtin_amdgcn_mfma_f32_16x16x32_bf16(a, b[c], acc[t][c], 0, 0, 0);
        }
    }

    // ---- store with per-token cluster select (c0 skipped; copy role owns it) ----
    int tA = gb + row16, tB = tA + 16;
    int idA = ids[tA], idB = ids[tB];
    int cA = idA < CUT0 ? 0 : (idA < CUT1 ? 1 : 2);
    int cB = idB < CUT0 ? 0 : (idB < CUT1 ? 1 : 2);
#pragma unroll
    for (int t = 0; t < 4; t++) {
        int d0 = wdb + t * 16 + kg * 4;
        float4 v1 = *(const float4*)(b1 + d0);
        float4 v2 = *(const float4*)(b2 + d0);
        if (cA) {
            float4 bs = (cA == 1) ? v1 : v2;
            float4 o = { acc[t][0][0] + bs.x, acc[t][0][1] + bs.y,
                         acc[t][0][2] + bs.z, acc[t][0][3] + bs.w };
            *(float4*)(out + (size_t)tA * D + d0) = o;
        }
        if (cB) {
            float4 bs = (cB == 1) ? v1 : v2;
            float4 o = { acc[t][1][0] + bs.x, acc[t][1][1] + bs.y,
                         acc[t][1][2] + bs.z, acc[t][1][3] + bs.w };
            *(float4*)(out + (size_t)tB * D + d0) = o;
        }
    }
}

extern "C" void kernel_launch(void* const* d_in, const int* in_sizes, int n_in,
                              void* d_out, int out_size, void* d_ws, size_t ws_size,
                              hipStream_t stream) {
    const int*   ids  = (const int*)d_in[0];
    const float* emb0 = (const float*)d_in[1];
    const float* emb1 = (const float*)d_in[2];
    const float* emb2 = (const float*)d_in[3];
    const float* w1   = (const float*)d_in[4];
    const float* b1   = (const float*)d_in[5];
    const float* w2   = (const float*)d_in[6];
    const float* b2   = (const float*)d_in[7];
    float* out = (float*)d_out;

    __bf16* w1b = (__bf16*)d_ws;
    __bf16* w2b = w1b + (size_t)D * D1;

    // (D*D1 + D*D2) / 512 = 640 blocks
    hipLaunchKernelGGL(k_cast, dim3(640), dim3(512), 0, stream, w1, w2, w1b, w2b);
    // 256 copy blocks + 2048 gemm blocks
    hipLaunchKernelGGL(k_mega, dim3(2304), dim3(512), 0, stream,
                       ids, emb0, emb1, emb2, b1, b2, w1b, w2b, out);
}

// Round 11
// 104.756 us; speedup vs baseline: 1.0927x; 1.0927x over previous
//
#include <hip/hip_runtime.h>

#define CUT0 20000
#define CUT1 60000
#define D    1024
#define D1   256
#define D2   64
#define NTOK 32768

typedef __bf16  bf16x8 __attribute__((ext_vector_type(8)));
typedef float   f32x4  __attribute__((ext_vector_type(4)));

// ws layout:
//   int      cnt[64]
//   unsigned list0/1/2[NTOK]         packed (tok<<17)|local_idx
//   __bf16   w1b[D*D1], w2b[D*D2]    ([d][k] layout, MFMA A-operand rows)

__global__ __launch_bounds__(256) void k_classify(
        const int* __restrict__ ids,
        const float* __restrict__ w1,
        const float* __restrict__ w2,
        int* cnt, unsigned* list0, unsigned* list1, unsigned* list2,
        __bf16* __restrict__ w1b, __bf16* __restrict__ w2b) {
    int bid = blockIdx.x, tid = threadIdx.x;
    if (bid < NTOK / 256) {
        unsigned t = bid * 256 + tid;
        int id = ids[t];
        int lane = tid & 63;
        unsigned long long lanebit = 1ull << lane;
        int c = (id < CUT0) ? 0 : (id < CUT1 ? 1 : 2);
        {
            unsigned long long m = __ballot(c == 0);
            if (m) {
                int base = 0;
                if (lane == 0) base = atomicAdd(cnt + 0, __popcll(m));
                base = __shfl(base, 0);
                if (c == 0) list0[base + __popcll(m & (lanebit - 1))] = (t << 17) | (unsigned)id;
            }
        }
        {
            unsigned long long m = __ballot(c == 1);
            if (m) {
                int base = 0;
                if (lane == 0) base = atomicAdd(cnt + 1, __popcll(m));
                base = __shfl(base, 0);
                if (c == 1) list1[base + __popcll(m & (lanebit - 1))] = (t << 17) | (unsigned)(id - CUT0);
            }
        }
        {
            unsigned long long m = __ballot(c == 2);
            if (m) {
                int base = 0;
                if (lane == 0) base = atomicAdd(cnt + 2, __popcll(m));
                base = __shfl(base, 0);
                if (c == 2) list2[base + __popcll(m & (lanebit - 1))] = (t << 17) | (unsigned)(id - CUT1);
            }
        }
    } else {
        int i = (bid - NTOK / 256) * 256 + tid;
        if (i < D1 * D) {
            w1b[i] = (__bf16)w1[i];
        } else {
            int j = i - D1 * D;
            w2b[j] = (__bf16)w2[j];
        }
    }
}

// Weight-stationary streaming GEMM role.
// Block pins W rows [s*64, s*64+64) x K in LDS (chunk-XOR swizzled), then each
// wave independently streams 16-token groups: B gathered from emb fp32 (global),
// A from LDS, 4 MFMA/ks, float4 stores. NO barriers after the W prologue.
// Fragments (verified rounds 4-10):
//   A: lane holds w d-row t*16+(lane&15) (slice-local), k=(lane>>4)*8+j (+32/ks)
//   B: lane holds token col (lane&15), same k slots
//   C/D: col=lane&15 (token), row=(lane>>4)*4+r (d) -> float4 store/lane
template<int K>
__device__ __forceinline__ void stream_gemm(
        const float* __restrict__ emb, const float* __restrict__ bias,
        float* __restrict__ out, const unsigned* __restrict__ list, int n,
        const __bf16* __restrict__ wb, int s, int bi, int nstride,
        int tid, __bf16* Ws) {
    constexpr int KS  = K / 32;
    constexpr int CH  = K / 8;                 // 16B chunks per W row
    constexpr int SWZ = (CH >= 16) ? 15 : 7;

    // prologue: stage W slice (64 rows x K) into LDS, swizzled. one-time.
    for (int idx = tid; idx < 64 * CH; idx += 512) {
        int r = idx / CH, c = idx % CH;
        bf16x8 v = *(const bf16x8*)(wb + (size_t)(s * 64 + r) * K + c * 8);
        *(bf16x8*)(Ws + r * K + ((c ^ (r & SWZ)) * 8)) = v;
    }
    __syncthreads();

    int lane = tid & 63, wv = tid >> 6;
    int col = lane & 15, kg = lane >> 4;
    int ng = (n + 15) >> 4;

    for (int g = bi * 8 + wv; g < ng; g += nstride) {
        int ti = g * 16 + col;
        unsigned p = list[ti < n ? ti : n - 1];
        unsigned lidx = p & 0x1FFFFu, tok = p >> 17;
        const float* ep = emb + (size_t)lidx * K + kg * 8;

        f32x4 acc[4];
#pragma unroll
        for (int t = 0; t < 4; t++) acc[t] = (f32x4){0.f, 0.f, 0.f, 0.f};

#pragma unroll
        for (int ks = 0; ks < KS; ks++) {
            float4 x = *(const float4*)(ep + ks * 32);
            float4 y = *(const float4*)(ep + ks * 32 + 4);
            bf16x8 b;
            b[0] = (__bf16)x.x; b[1] = (__bf16)x.y; b[2] = (__bf16)x.z; b[3] = (__bf16)x.w;
            b[4] = (__bf16)y.x; b[5] = (__bf16)y.y; b[6] = (__bf16)y.z; b[7] = (__bf16)y.w;
#pragma unroll
            for (int t = 0; t < 4; t++) {
                int dl = t * 16 + col;
                int ch = (kg + ks * 4) ^ (dl & SWZ);
                bf16x8 a = *(const bf16x8*)(Ws + dl * K + ch * 8);
                acc[t] = __builtin_amdgcn_mfma_f32_16x16x32_bf16(a, b, acc[t], 0, 0, 0);
            }
        }

        if (ti < n) {
            float* orow = out + (size_t)tok * D + s * 64 + kg * 4;
#pragma unroll
            for (int t = 0; t < 4; t++) {
                float4 bs = *(const float4*)(bias + s * 64 + t * 16 + kg * 4);
                float4 o = { acc[t][0] + bs.x, acc[t][1] + bs.y,
                             acc[t][2] + bs.z, acc[t][3] + bs.w };
                *(float4*)(orow + t * 16) = o;
            }
        }
    }
}

// grid: [0,256) c0 copy role; [256,512) c1 (16 slices x 16 blocks);
//       [512,896) c2 (16 slices x 24 blocks). 512 thr/block.
__global__ __launch_bounds__(512, 4) void k_stream(
        const float* __restrict__ emb0,
        const float* __restrict__ emb1,
        const float* __restrict__ emb2,
        const float* __restrict__ b1,
        const float* __restrict__ b2,
        float* __restrict__ out,
        const int* __restrict__ cnt,
        const unsigned* __restrict__ list0,
        const unsigned* __restrict__ list1,
        const unsigned* __restrict__ list2,
        const __bf16* __restrict__ w1b,
        const __bf16* __restrict__ w2b) {
    __shared__ __bf16 Ws[64 * 256];   // 32 KB (c1); c2 uses first 8 KB

    int bid = blockIdx.x, tid = threadIdx.x;

    if (bid < 256) {
        // ---- c0 copy role: grid-stride over list0, 2 rows per block-iter ----
        int n0 = cnt[0];
        int f = tid & 255;
        for (int r = bid * 2 + (tid >> 8); r < n0; r += 512) {
            unsigned p = list0[r];
            const float4* src = (const float4*)(emb0 + (size_t)(p & 0x1FFFFu) * D);
            float4* dst = (float4*)(out + (size_t)(p >> 17) * D);
            dst[f] = src[f];
        }
    } else if (bid < 512) {
        int e = bid - 256;
        stream_gemm<D1>(emb1, b1, out, list1, cnt[1], w1b,
                        e & 15, e >> 4, 16 * 8, tid, Ws);
    } else {
        int e = bid - 512;
        stream_gemm<D2>(emb2, b2, out, list2, cnt[2], w2b,
                        e & 15, e >> 4, 24 * 8, tid, Ws);
    }
}

extern "C" void kernel_launch(void* const* d_in, const int* in_sizes, int n_in,
                              void* d_out, int out_size, void* d_ws, size_t ws_size,
                              hipStream_t stream) {
    const int*   ids  = (const int*)d_in[0];
    const float* emb0 = (const float*)d_in[1];
    const float* emb1 = (const float*)d_in[2];
    const float* emb2 = (const float*)d_in[3];
    const float* w1   = (const float*)d_in[4];
    const float* b1   = (const float*)d_in[5];
    const float* w2   = (const float*)d_in[6];
    const float* b2   = (const float*)d_in[7];
    float* out = (float*)d_out;

    int* cnt        = (int*)d_ws;
    unsigned* list0 = (unsigned*)((char*)d_ws + 256);
    unsigned* list1 = list0 + NTOK;
    unsigned* list2 = list1 + NTOK;
    __bf16* w1b     = (__bf16*)(list2 + NTOK);
    __bf16* w2b     = w1b + (size_t)D * D1;

    hipMemsetAsync(cnt, 0, 3 * sizeof(int), stream);
    hipLaunchKernelGGL(k_classify, dim3(NTOK / 256 + 1280), dim3(256), 0, stream,
                       ids, w1, w2, cnt, list0, list1, list2, w1b, w2b);
    hipLaunchKernelGGL(k_stream, dim3(896), dim3(512), 0, stream,
                       emb0, emb1, emb2, b1, b2, out, cnt,
                       list0, list1, list2, w1b, w2b);
}